// Round 3
// baseline (217.374 us; speedup 1.0000x reference)
//
#include <hip/hip_runtime.h>
#include <math.h>

// Problem constants
#define TT   4096
#define NBB  32
#define NUU  64
#define NHH  256
#define HH   128
#define NYY  64
// Chunking: 512 chunks of 8 steps; carry hierarchy: 16 supers x 32 chunks
#define LCH  8
#define CCH  512
#define SEGN 16
#define CPS  32

#define PI_HALF 1.5707963267948966f

typedef float  f32x16 __attribute__((ext_vector_type(16)));
typedef __bf16 bf16x8 __attribute__((ext_vector_type(8)));
typedef __bf16 bf16x2 __attribute__((ext_vector_type(2)));
typedef unsigned int uint4v __attribute__((ext_vector_type(4)));

// MFMA 32x32 C/D layout: row = (r&3) + 8*(r>>2) + 4*(lane>>5), col = lane&31
__device__ inline int crow(int r, int lane) { return (r & 3) + 8 * (r >> 2) + 4 * (lane >> 5); }
__device__ inline bf16x8 ldfrag(const unsigned short* p) {
    return __builtin_bit_cast(bf16x8, *(const uint4v*)p);
}

// split a float into bf16 hi + bf16 lo (hi+lo ~ exact to 2^-17 rel)
#define CVT(v, H, L) { __bf16 _h = (__bf16)(v); H = _h; L = (__bf16)((v) - (float)_h); }

// lambda in fp32 with correctly-rounded transcendentals (double -> fp32)
__device__ inline void lam_f32(float xre, float xim, float& lr, float& li) {
    float th = PI_HALF * xim;
    float rf = (float)exp(-(double)fabsf(xre));
    float cf = (float)cos((double)th);
    float sf = (float)sin((double)th);
    lr = rf * cf; li = rf * sf;
}

// sX swizzle (offsets in shorts): row stride 512, low-5 of 16B-chunk ^= row
__device__ inline int swzX(int row, int so) {
    int chv = so >> 3;
    chv = (chv & 32) | ((chv ^ row) & 31);
    return row * 512 + (chv << 3) + (so & 7);
}

// ---------------------------------------------------------------------------
// Prep (grid 4256):
//  bx 0..31     : x0 pairs
//  bx 32..95    : split B (plain) and W_x2y (interleaved K permute)
//  bx 96..159   : B' = lambda^{7-j}-weighted B, split  (256 x 512, K=(j,u))
//  bx 160..4255 : U fp32 -> Uh/Ul split-bf16 (8.4M elems)
// ---------------------------------------------------------------------------
__global__ __launch_bounds__(256) void k_prep(
    const float* __restrict__ B, const float* __restrict__ W,
    const float* __restrict__ y0, const float* __restrict__ Wy2x,
    const float* __restrict__ by2x,
    const float* __restrict__ lre, const float* __restrict__ lim,
    const float* __restrict__ U,
    unsigned short* __restrict__ Bph, unsigned short* __restrict__ Bpl,
    unsigned short* __restrict__ Wph, unsigned short* __restrict__ Wpl,
    unsigned short* __restrict__ Bqh, unsigned short* __restrict__ Bql,
    unsigned short* __restrict__ Uh,  unsigned short* __restrict__ Ul,
    float2* __restrict__ x0p)
{
    int bx = blockIdx.x, tid = threadIdx.x;
    if (bx < 32) {
        if (tid < HH) {
            int b = bx, ch = tid;
            float xr = by2x[ch], xi = by2x[ch + HH];
            for (int y = 0; y < NYY; ++y) {
                float v = y0[b * NYY + y];
                xr += v * Wy2x[ch * NYY + y];
                xi += v * Wy2x[(ch + HH) * NYY + y];
            }
            x0p[b * HH + ch] = make_float2(xr, xi);
        }
    } else if (bx < 96) {
        int i = (bx - 32) * 256 + tid;            // 0..16383
        float bv = B[i];
        __bf16 bh = (__bf16)bv;
        Bph[i] = __builtin_bit_cast(unsigned short, bh);
        Bpl[i] = __builtin_bit_cast(unsigned short, (__bf16)(bv - (float)bh));
        int y = i >> 8, kidx = i & 255;
        float wv = W[y * NHH + (kidx & 1) * HH + (kidx >> 1)];
        __bf16 wh = (__bf16)wv;
        Wph[i] = __builtin_bit_cast(unsigned short, wh);
        Wpl[i] = __builtin_bit_cast(unsigned short, (__bf16)(wv - (float)wh));
    } else if (bx < 160) {
        // B' rows: 0..127 = re-out (ch=row), 128..255 = im-out (ch=row-128)
        // col = j*64 + u; B'_re = lr7j*B[ch][u] - li7j*B[ch+128][u]
        //                 B'_im = li7j*B[ch][u] + lr7j*B[ch+128][u]
        int e = (bx - 96) * 2048 + tid * 8;       // 0..131064, 8 elems/thread
        int row = e >> 9, col = e & 511;
        int j = col >> 6, u = col & 63;
        int ch = (row < HH) ? row : (row - HH);
        float lrf, lif; lam_f32(lre[ch], lim[ch], lrf, lif);
        double pr = 1.0, pi_ = 0.0;
        for (int s = 0; s < 7 - j; ++s) {
            double nr = pr * (double)lrf - pi_ * (double)lif;
            double ni = pr * (double)lif + pi_ * (double)lrf;
            pr = nr; pi_ = ni;
        }
        for (int k = 0; k < 8; ++k) {
            double b0 = (double)B[ch * NUU + u + k];
            double b1 = (double)B[(ch + HH) * NUU + u + k];
            float val = (row < HH) ? (float)(pr * b0 - pi_ * b1)
                                   : (float)(pi_ * b0 + pr * b1);
            __bf16 vh = (__bf16)val;
            Bqh[e + k] = __builtin_bit_cast(unsigned short, vh);
            Bql[e + k] = __builtin_bit_cast(unsigned short, (__bf16)(val - (float)vh));
        }
    } else {
        int e0 = (bx - 160) * 2048 + tid * 8;     // 8 floats per thread
        const float4* s = (const float4*)(U + e0);
        float4 f0 = s[0], f1 = s[1];
        bf16x8 h, l;
        CVT(f0.x, h[0], l[0]); CVT(f0.y, h[1], l[1]); CVT(f0.z, h[2], l[2]); CVT(f0.w, h[3], l[3]);
        CVT(f1.x, h[4], l[4]); CVT(f1.y, h[5], l[5]); CVT(f1.z, h[6], l[6]); CVT(f1.w, h[7], l[7]);
        *(bf16x8*)&Uh[e0] = h;
        *(bf16x8*)&Ul[e0] = l;
    }
}

// ---------------------------------------------------------------------------
// Pass 1 (v3): pure GEMM, zero LDS, zero barriers.
// E[c] (32b x 256ch) = U_tile(32 x 512) @ B'^T(512 x 256), 3-term split.
// Wave w: N-tiles nt=0 (re rows ch=w*32+l31) and nt=1 (im rows 128+ch).
// ---------------------------------------------------------------------------
__global__ __launch_bounds__(256) void k_pass1(
    const unsigned short* __restrict__ Uh, const unsigned short* __restrict__ Ul,
    const unsigned short* __restrict__ Bqh, const unsigned short* __restrict__ Bql,
    float2* __restrict__ E)
{
    const int tid = threadIdx.x, w = tid >> 6, lane = tid & 63;
    const int l31 = lane & 31, kh = lane >> 5;
    const int c = blockIdx.x;
    const int ch = w * 32 + l31;

    const unsigned short* uh = Uh + (size_t)c * (LCH * NBB * NUU) + l31 * 64 + kh * 8;
    const unsigned short* ul = Ul + (size_t)c * (LCH * NBB * NUU) + l31 * 64 + kh * 8;
    const unsigned short* b0h = Bqh + (size_t)ch * 512 + kh * 8;
    const unsigned short* b1h = Bqh + (size_t)(HH + ch) * 512 + kh * 8;
    const unsigned short* b0l = Bql + (size_t)ch * 512 + kh * 8;
    const unsigned short* b1l = Bql + (size_t)(HH + ch) * 512 + kh * 8;

    f32x16 acc0, acc1;
#pragma unroll
    for (int r = 0; r < 16; ++r) { acc0[r] = 0.f; acc1[r] = 0.f; }

#pragma unroll 4
    for (int kk = 0; kk < 32; ++kk) {
        int uoff = (kk >> 2) * 2048 + (kk & 3) * 16;   // (j*32 rows)*64 + u-base
        int koff = kk * 16;
        bf16x8 ah  = ldfrag(uh + uoff);
        bf16x8 al  = ldfrag(ul + uoff);
        bf16x8 bh0 = ldfrag(b0h + koff);
        bf16x8 bh1 = ldfrag(b1h + koff);
        bf16x8 bl0 = ldfrag(b0l + koff);
        bf16x8 bl1 = ldfrag(b1l + koff);
        acc0 = __builtin_amdgcn_mfma_f32_32x32x16_bf16(ah, bh0, acc0, 0, 0, 0);
        acc1 = __builtin_amdgcn_mfma_f32_32x32x16_bf16(ah, bh1, acc1, 0, 0, 0);
        acc0 = __builtin_amdgcn_mfma_f32_32x32x16_bf16(al, bh0, acc0, 0, 0, 0);
        acc1 = __builtin_amdgcn_mfma_f32_32x32x16_bf16(al, bh1, acc1, 0, 0, 0);
        acc0 = __builtin_amdgcn_mfma_f32_32x32x16_bf16(ah, bl0, acc0, 0, 0, 0);
        acc1 = __builtin_amdgcn_mfma_f32_32x32x16_bf16(ah, bl1, acc1, 0, 0, 0);
    }

#pragma unroll
    for (int r = 0; r < 16; ++r)
        E[(size_t)c * 4096 + crow(r, lane) * HH + ch] = make_float2(acc0[r], acc1[r]);
}

// ---------------------------------------------------------------------------
// Carry hierarchy. chain = b*128 + ch (4096 chains). Powers of the fp32
// lambda computed EXACTLY (double squaring), recurrences in double.
// ---------------------------------------------------------------------------
__global__ __launch_bounds__(256) void k_cseg(
    const float* __restrict__ lre, const float* __restrict__ lim,
    const float2* __restrict__ E, float2* __restrict__ Esup)
{
    int g = blockIdx.x * 256 + threadIdx.x;
    int chain = g & 4095, seg = g >> 12, ch = chain & 127;
    float lrf, lif; lam_f32(lre[ch], lim[ch], lrf, lif);
    double pr = (double)lrf, pi = (double)lif;
#pragma unroll
    for (int s = 0; s < 3; ++s) { double nr = pr*pr - pi*pi, ni = 2.0*pr*pi; pr = nr; pi = ni; } // lambda^8
    double sr = 0.0, si = 0.0;
#pragma unroll 8
    for (int j = 0; j < CPS; ++j) {
        float2 e = E[((size_t)seg * CPS + j) * 4096 + chain];
        double nr = pr * sr - pi * si + (double)e.x;
        double ni = pi * sr + pr * si + (double)e.y;
        sr = nr; si = ni;
    }
    Esup[(size_t)seg * 4096 + chain] = make_float2((float)sr, (float)si);
}

__global__ __launch_bounds__(256) void k_csup(
    const float* __restrict__ lre, const float* __restrict__ lim,
    const float2* __restrict__ x0p, const float2* __restrict__ Esup,
    float2* __restrict__ CarrySup)
{
    int chain = blockIdx.x * 256 + threadIdx.x;   // grid 16 -> 0..4095
    int ch = chain & 127;
    float lrf, lif; lam_f32(lre[ch], lim[ch], lrf, lif);
    double pr = (double)lrf, pi = (double)lif;
#pragma unroll
    for (int s = 0; s < 8; ++s) { double nr = pr*pr - pi*pi, ni = 2.0*pr*pi; pr = nr; pi = ni; } // lambda^256
    float2 c0 = x0p[chain];
    double cr = (double)c0.x, ci = (double)c0.y;
#pragma unroll
    for (int s = 0; s < SEGN; ++s) {
        CarrySup[(size_t)s * 4096 + chain] = make_float2((float)cr, (float)ci);
        float2 e = Esup[(size_t)s * 4096 + chain];
        double nr = pr * cr - pi * ci + (double)e.x;
        double ni = pi * cr + pr * ci + (double)e.y;
        cr = nr; ci = ni;
    }
}

__global__ __launch_bounds__(256) void k_cexp(
    const float* __restrict__ lre, const float* __restrict__ lim,
    const float2* __restrict__ E, const float2* __restrict__ CarrySup,
    float2* __restrict__ Carry)
{
    int g = blockIdx.x * 256 + threadIdx.x;
    int chain = g & 4095, seg = g >> 12, ch = chain & 127;
    float lrf, lif; lam_f32(lre[ch], lim[ch], lrf, lif);
    double pr = (double)lrf, pi = (double)lif;
#pragma unroll
    for (int s = 0; s < 3; ++s) { double nr = pr*pr - pi*pi, ni = 2.0*pr*pi; pr = nr; pi = ni; } // lambda^8
    float2 cc = CarrySup[(size_t)seg * 4096 + chain];
    double cr = (double)cc.x, ci = (double)cc.y;
#pragma unroll 8
    for (int j = 0; j < CPS; ++j) {
        size_t idx = ((size_t)seg * CPS + j) * 4096 + chain;
        Carry[idx] = make_float2((float)cr, (float)ci);
        float2 e = E[idx];
        double nr = pr * cr - pi * ci + (double)e.x;
        double ni = pi * cr + pr * ci + (double)e.y;
        cr = nr; ci = ni;
    }
}

// ---------------------------------------------------------------------------
// Pass 2 (v3): seeded scan + fused output GEMM.
// LDS = sX only (64 KB) -> 2 blocks/CU. U fragments straight from Uh/Ul
// (global, L1-hot, shared by all 4 waves). B-fragments per-kk from L2.
// Per sub: [out-GEMM(sub-1)] -> bar -> [Bu MFMA + scan + dump sX] -> bar.
// ---------------------------------------------------------------------------
__global__ __launch_bounds__(256, 1) void k_pass2(
    const unsigned short* __restrict__ Uh, const unsigned short* __restrict__ Ul,
    const unsigned short* __restrict__ Bph, const unsigned short* __restrict__ Bpl,
    const unsigned short* __restrict__ Wph, const unsigned short* __restrict__ Wpl,
    const float* __restrict__ lre, const float* __restrict__ lim,
    const float* __restrict__ bx2y,
    const float2* __restrict__ Carry, float* __restrict__ Y)
{
    __shared__ __align__(16) unsigned short sX[64 * 512];   // 65536 B, swizzled

    const int tid = threadIdx.x, w = tid >> 6, lane = tid & 63;
    const int l31 = lane & 31, kh = lane >> 5;
    const int c = blockIdx.x;
    const int ch = w * 32 + l31;             // scan channel
    const int mtile = w & 1, ntile = w >> 1; // out-GEMM tile mapping

    float lr, li; lam_f32(lre[ch], lim[ch], lr, li);
    float ybias = bx2y[ntile * 32 + l31];

    // U fragment bases (per-lane): row (t*32 + l31), 16B chunk at kh*8
    const unsigned short* uhb = Uh + (size_t)(c * LCH) * (NBB * NUU) + l31 * 64 + kh * 8;
    const unsigned short* ulb = Ul + (size_t)(c * LCH) * (NBB * NUU) + l31 * 64 + kh * 8;
    // B fragment bases
    const unsigned short* b0h = Bph + (size_t)ch * NUU + kh * 8;
    const unsigned short* b1h = Bph + (size_t)(HH + ch) * NUU + kh * 8;
    const unsigned short* b0l = Bpl + (size_t)ch * NUU + kh * 8;
    const unsigned short* b1l = Bpl + (size_t)(HH + ch) * NUU + kh * 8;

    // Hoist W fragments (hi + lo) once per block (64 VGPR)
    bf16x8 wfh[16], wfl[16];
#pragma unroll
    for (int kk = 0; kk < 16; ++kk) {
        wfh[kk] = ldfrag(&Wph[(size_t)(ntile * 32 + l31) * NHH + kk * 16 + kh * 8]);
        wfl[kk] = ldfrag(&Wpl[(size_t)(ntile * 32 + l31) * NHH + kk * 16 + kh * 8]);
    }

    // Seed from Carry
    float zr[16], zi[16];
#pragma unroll
    for (int r = 0; r < 16; ++r) {
        float2 v = Carry[(size_t)c * 4096 + crow(r, lane) * HH + ch];
        zr[r] = v.x; zi[r] = v.y;
    }

    for (int sub = 0; sub < 4; ++sub) {
        if (sub > 0) {  // out-GEMM for sub-1 (reads sX written before last barrier)
            f32x16 ya0, ya1, ya2;
#pragma unroll
            for (int r = 0; r < 16; ++r) { ya0[r] = 0.f; ya1[r] = 0.f; ya2[r] = 0.f; }
#pragma unroll
            for (int kk = 0; kk < 16; ++kk) {
                bf16x8 xah = ldfrag(&sX[swzX(mtile * 32 + l31, kk * 16 + kh * 8)]);
                bf16x8 xal = ldfrag(&sX[swzX(mtile * 32 + l31, 256 + kk * 16 + kh * 8)]);
                ya0 = __builtin_amdgcn_mfma_f32_32x32x16_bf16(xah, wfh[kk], ya0, 0, 0, 0);
                ya1 = __builtin_amdgcn_mfma_f32_32x32x16_bf16(xal, wfh[kk], ya1, 0, 0, 0);
                ya2 = __builtin_amdgcn_mfma_f32_32x32x16_bf16(xah, wfl[kk], ya2, 0, 0, 0);
            }
            int t = c * LCH + (sub - 1) * 2 + mtile;
#pragma unroll
            for (int r = 0; r < 16; ++r)
                Y[((size_t)t * NBB + crow(r, lane)) * NYY + ntile * 32 + l31] =
                    (ya0[r] + ya1[r]) + ya2[r] + ybias;
        }
        __syncthreads();

        // Bu MFMA (split 3-term); A from global (L1-hot), B per-kk from L2
        f32x16 acc[2][2];
#pragma unroll
        for (int mt = 0; mt < 2; ++mt)
#pragma unroll
            for (int nt = 0; nt < 2; ++nt)
#pragma unroll
                for (int r = 0; r < 16; ++r) acc[mt][nt][r] = 0.f;

        const size_t t0off = (size_t)(sub * 2) * (NBB * NUU);
#pragma unroll
        for (int kk = 0; kk < 4; ++kk) {
            bf16x8 a0h = ldfrag(uhb + t0off + kk * 16);
            bf16x8 a1h = ldfrag(uhb + t0off + (NBB * NUU) + kk * 16);
            bf16x8 a0l = ldfrag(ulb + t0off + kk * 16);
            bf16x8 a1l = ldfrag(ulb + t0off + (NBB * NUU) + kk * 16);
            bf16x8 bh0 = ldfrag(b0h + kk * 16);
            bf16x8 bh1 = ldfrag(b1h + kk * 16);
            bf16x8 bl0 = ldfrag(b0l + kk * 16);
            bf16x8 bl1 = ldfrag(b1l + kk * 16);
            acc[0][0] = __builtin_amdgcn_mfma_f32_32x32x16_bf16(a0h, bh0, acc[0][0], 0, 0, 0);
            acc[0][1] = __builtin_amdgcn_mfma_f32_32x32x16_bf16(a0h, bh1, acc[0][1], 0, 0, 0);
            acc[1][0] = __builtin_amdgcn_mfma_f32_32x32x16_bf16(a1h, bh0, acc[1][0], 0, 0, 0);
            acc[1][1] = __builtin_amdgcn_mfma_f32_32x32x16_bf16(a1h, bh1, acc[1][1], 0, 0, 0);
            acc[0][0] = __builtin_amdgcn_mfma_f32_32x32x16_bf16(a0l, bh0, acc[0][0], 0, 0, 0);
            acc[0][1] = __builtin_amdgcn_mfma_f32_32x32x16_bf16(a0l, bh1, acc[0][1], 0, 0, 0);
            acc[1][0] = __builtin_amdgcn_mfma_f32_32x32x16_bf16(a1l, bh0, acc[1][0], 0, 0, 0);
            acc[1][1] = __builtin_amdgcn_mfma_f32_32x32x16_bf16(a1l, bh1, acc[1][1], 0, 0, 0);
            acc[0][0] = __builtin_amdgcn_mfma_f32_32x32x16_bf16(a0h, bl0, acc[0][0], 0, 0, 0);
            acc[0][1] = __builtin_amdgcn_mfma_f32_32x32x16_bf16(a0h, bl1, acc[0][1], 0, 0, 0);
            acc[1][0] = __builtin_amdgcn_mfma_f32_32x32x16_bf16(a1h, bl0, acc[1][0], 0, 0, 0);
            acc[1][1] = __builtin_amdgcn_mfma_f32_32x32x16_bf16(a1h, bl1, acc[1][1], 0, 0, 0);
        }

        // Scan + split hi/lo dump (two b32 per (mt,r)), swizzled
#pragma unroll
        for (int mt = 0; mt < 2; ++mt)
#pragma unroll
            for (int r = 0; r < 16; ++r) {
                float t0 = fmaf(lr, zr[r], acc[mt][0][r]); t0 = fmaf(-li, zi[r], t0);
                float t1 = fmaf(li, zr[r], acc[mt][1][r]); t1 = fmaf(lr, zi[r], t1);
                zr[r] = t0; zi[r] = t1;
                bf16x2 hv, lv;
                { __bf16 _h = (__bf16)t0; hv[0] = _h; lv[0] = (__bf16)(t0 - (float)_h); }
                { __bf16 _h = (__bf16)t1; hv[1] = _h; lv[1] = (__bf16)(t1 - (float)_h); }
                int row = mt * 32 + crow(r, lane);
                *(bf16x2*)&sX[swzX(row, w * 64 + 2 * l31)]       = hv;
                *(bf16x2*)&sX[swzX(row, 256 + w * 64 + 2 * l31)] = lv;
            }
        __syncthreads();
    }

    // Drain: out-GEMM for sub=3
    {
        f32x16 ya0, ya1, ya2;
#pragma unroll
        for (int r = 0; r < 16; ++r) { ya0[r] = 0.f; ya1[r] = 0.f; ya2[r] = 0.f; }
#pragma unroll
        for (int kk = 0; kk < 16; ++kk) {
            bf16x8 xah = ldfrag(&sX[swzX(mtile * 32 + l31, kk * 16 + kh * 8)]);
            bf16x8 xal = ldfrag(&sX[swzX(mtile * 32 + l31, 256 + kk * 16 + kh * 8)]);
            ya0 = __builtin_amdgcn_mfma_f32_32x32x16_bf16(xah, wfh[kk], ya0, 0, 0, 0);
            ya1 = __builtin_amdgcn_mfma_f32_32x32x16_bf16(xal, wfh[kk], ya1, 0, 0, 0);
            ya2 = __builtin_amdgcn_mfma_f32_32x32x16_bf16(xah, wfl[kk], ya2, 0, 0, 0);
        }
        int t = c * LCH + 3 * 2 + mtile;
#pragma unroll
        for (int r = 0; r < 16; ++r)
            Y[((size_t)t * NBB + crow(r, lane)) * NYY + ntile * 32 + l31] =
                (ya0[r] + ya1[r]) + ya2[r] + ybias;
    }
}

// ---------------------------------------------------------------------------
extern "C" void kernel_launch(void* const* d_in, const int* in_sizes, int n_in,
                              void* d_out, int out_size, void* d_ws, size_t ws_size,
                              hipStream_t stream) {
    const float* y0    = (const float*)d_in[0];
    const float* U     = (const float*)d_in[1];
    const float* lre   = (const float*)d_in[2];
    const float* lim   = (const float*)d_in[3];
    const float* B     = (const float*)d_in[4];
    const float* W_y2x = (const float*)d_in[5];
    const float* b_y2x = (const float*)d_in[6];
    const float* W_x2y = (const float*)d_in[7];
    const float* b_x2y = (const float*)d_in[8];
    float* Y = (float*)d_out;

    char* p = (char*)d_ws;
    float2* E        = (float2*)p; p += (size_t)CCH * 4096 * sizeof(float2);   // 16.8 MB
    float2* Carry    = (float2*)p; p += (size_t)CCH * 4096 * sizeof(float2);   // 16.8 MB
    float2* Esup     = (float2*)p; p += (size_t)SEGN * 4096 * sizeof(float2);  // 512 KB
    float2* CarrySup = (float2*)p; p += (size_t)SEGN * 4096 * sizeof(float2);  // 512 KB
    float2* x0p      = (float2*)p; p += (size_t)4096 * sizeof(float2);         // 32 KB
    unsigned short* Bph = (unsigned short*)p; p += 16384 * sizeof(unsigned short);
    unsigned short* Bpl = (unsigned short*)p; p += 16384 * sizeof(unsigned short);
    unsigned short* Wph = (unsigned short*)p; p += 16384 * sizeof(unsigned short);
    unsigned short* Wpl = (unsigned short*)p; p += 16384 * sizeof(unsigned short);
    unsigned short* Bqh = (unsigned short*)p; p += (size_t)NHH * 512 * sizeof(unsigned short); // 256 KB
    unsigned short* Bql = (unsigned short*)p; p += (size_t)NHH * 512 * sizeof(unsigned short); // 256 KB
    unsigned short* Uh  = (unsigned short*)p; p += (size_t)TT * NBB * NUU * sizeof(unsigned short); // 16.8 MB
    unsigned short* Ul  = (unsigned short*)p; p += (size_t)TT * NBB * NUU * sizeof(unsigned short); // 16.8 MB

    k_prep <<<dim3(4256), dim3(256), 0, stream>>>(B, W_x2y, y0, W_y2x, b_y2x,
                                                  lre, lim, U,
                                                  Bph, Bpl, Wph, Wpl,
                                                  Bqh, Bql, Uh, Ul, x0p);
    k_pass1<<<dim3(CCH), dim3(256), 0, stream>>>(Uh, Ul, Bqh, Bql, E);
    k_cseg <<<dim3(256), dim3(256), 0, stream>>>(lre, lim, E, Esup);
    k_csup <<<dim3(16),  dim3(256), 0, stream>>>(lre, lim, x0p, Esup, CarrySup);
    k_cexp <<<dim3(256), dim3(256), 0, stream>>>(lre, lim, E, CarrySup, Carry);
    k_pass2<<<dim3(CCH), dim3(256), 0, stream>>>(Uh, Ul, Bph, Bpl, Wph, Wpl,
                                                 lre, lim, b_x2y, Carry, Y);
}